// Round 14
// baseline (209.137 us; speedup 1.0000x reference)
//
#include <hip/hip_runtime.h>
#include <stdint.h>

// Problem constants
#define NSITES 784          // 4 * 196
#define LSZ    196          // 14*14
#define HWD    14
#define KKA_   288
#define BD_    512
#define NRG    6            // row-groups (288/48)
#define ROWS_PER_BLK 48
#define ROWS_PER_WAVE 12    // 48 / 4 waves (even: 2-step prefetch loop)
#define SITES_PER_BLK 4

// workspace layout (bytes)
#define WH_OFF    0            // W fp16 (transposed): 288*512*8*2 = 2,359,296
#define XH_OFF    2359296      // x fp16: 784*288*8*2      = 3,612,672
#define PART_OFF  5971968      // partial: 784*6*512*4     = 9,633,792
#define VBUF_OFF  15605760     // v: 784*512*4             = 1,605,632
#define WS_NEED   17211392

typedef _Float16 h2 __attribute__((ext_vector_type(2)));

// keep 8 floats pinned in VGPRs
#define PIN8(p) asm volatile("" : "+v"(p[0]),"+v"(p[1]),"+v"(p[2]),"+v"(p[3]), \
                                  "+v"(p[4]),"+v"(p[5]),"+v"(p[6]),"+v"(p[7]))

// 8-term fp16 dot with fp32 accumulate
__device__ __forceinline__ float dot8(const uint4 wv, const uint4 xv) {
    h2 w0 = __builtin_bit_cast(h2, wv.x), w1 = __builtin_bit_cast(h2, wv.y),
       w2 = __builtin_bit_cast(h2, wv.z), w3 = __builtin_bit_cast(h2, wv.w);
    h2 x0 = __builtin_bit_cast(h2, xv.x), x1 = __builtin_bit_cast(h2, xv.y),
       x2 = __builtin_bit_cast(h2, xv.z), x3 = __builtin_bit_cast(h2, xv.w);
#if __has_builtin(__builtin_amdgcn_fdot2)
    float acc = __builtin_amdgcn_fdot2(w0, x0, 0.f, false);
    acc = __builtin_amdgcn_fdot2(w1, x1, acc, false);
    acc = __builtin_amdgcn_fdot2(w2, x2, acc, false);
    acc = __builtin_amdgcn_fdot2(w3, x3, acc, false);
    return acc;
#else
    float acc = (float)w0.x*(float)x0.x + (float)w0.y*(float)x0.y
              + (float)w1.x*(float)x1.x + (float)w1.y*(float)x1.y
              + (float)w2.x*(float)x2.x + (float)w2.y*(float)x2.y
              + (float)w3.x*(float)x3.x + (float)w3.y*(float)x3.y;
    return acc;
#endif
}

// ---------------- k_prep: W -> fp16 (transposed), x-patch gather -> fp16 ----
__global__ __launch_bounds__(256) void k_prep(
    const float* __restrict__ pose, const float* __restrict__ W,
    uint4* __restrict__ Wh, uint4* __restrict__ xh)
{
    const int t  = threadIdx.x;
    const int bx = blockIdx.x;
    if (bx < NSITES) {
        const int site = bx;
        const int b = site / LSZ;
        const int l = site - b * LSZ;
        const int oh = l / HWD, ow = l - oh * HWD;
        for (int kk = t; kk < KKA_; kk += 256) {
            const int p = kk >> 5, a = kk & 31;
            const int ky = p / 3 - 1, kx = p % 3 - 1;
            const int y = oh + ky, x = ow + kx;
            const bool inb = (y >= 0 && y < HWD && x >= 0 && x < HWD);
            const float* pp = pose + ((size_t)b * 256 + a * 8) * LSZ
                            + (inb ? (y * HWD + x) : 0);
            uint32_t uo[4];
            #pragma unroll
            for (int cp = 0; cp < 4; ++cp) {
                const float f0 = inb ? pp[(2*cp)   * LSZ] : 0.f;
                const float f1 = inb ? pp[(2*cp+1) * LSZ] : 0.f;
                h2 hh; hh.x = (_Float16)f0; hh.y = (_Float16)f1;
                uo[cp] = __builtin_bit_cast(uint32_t, hh);
            }
            uint4 o; o.x = uo[0]; o.y = uo[1]; o.z = uo[2]; o.w = uo[3];
            xh[(size_t)site * KKA_ + kk] = o;
        }
    } else {
        const int wb = bx - NSITES;
        const int kk = wb * 4 + (t >> 6);
        const int ln = t & 63;
        const float* Wr = W + (size_t)kk * (BD_ * 8);
        #pragma unroll
        for (int u = 0; u < 8; ++u) {
            const int p = ln * 8 + u;
            const float4 fa = *(const float4*)(Wr + p * 8);
            const float4 fb = *(const float4*)(Wr + p * 8 + 4);
            uint32_t uo[4];
            h2 h0; h0.x=(_Float16)fa.x; h0.y=(_Float16)fa.y; uo[0]=__builtin_bit_cast(uint32_t,h0);
            h2 h1; h1.x=(_Float16)fa.z; h1.y=(_Float16)fa.w; uo[1]=__builtin_bit_cast(uint32_t,h1);
            h2 hv; hv.x=(_Float16)fb.x; hv.y=(_Float16)fb.y; uo[2]=__builtin_bit_cast(uint32_t,hv);
            h2 h3; h3.x=(_Float16)fb.z; h3.y=(_Float16)fb.w; uo[3]=__builtin_bit_cast(uint32_t,h3);
            uint4 o; o.x=uo[0]; o.y=uo[1]; o.z=uo[2]; o.w=uo[3];
            Wh[(size_t)kk * 512 + u * 64 + ln] = o;   // coalesced over ln
        }
    }
}

// ---- per-row compute: 4 sites against one W row (wr), staged softmax ------
template<int PASS>
__device__ __forceinline__ void row_body(
    const uint4 wr[8], const uint4* __restrict__ xrow, int site0,
    const float v[SITES_PER_BLK][8], float sacc[SITES_PER_BLK][8])
{
    if (PASS == 1) {
        #pragma unroll
        for (int s = 0; s < SITES_PER_BLK; ++s) {
            const uint4 xr = xrow[(size_t)(site0 + s) * KKA_];  // uniform -> s_load
            #pragma unroll
            for (int j = 0; j < 8; ++j) sacc[s][j] += dot8(wr[j], xr);
        }
    } else {
        // stage A: all 4 sites' po + logit dot (independent -> ILP)
        float po[SITES_PER_BLK][8];
        float up[SITES_PER_BLK];
        #pragma unroll
        for (int s = 0; s < SITES_PER_BLK; ++s) {
            const uint4 xr = xrow[(size_t)(site0 + s) * KKA_];
            #pragma unroll
            for (int j = 0; j < 8; ++j) po[s][j] = dot8(wr[j], xr);
            float u = v[s][0] * po[s][0];
            #pragma unroll
            for (int j = 1; j < 8; ++j) u += v[s][j] * po[s][j];
            up[s] = u;
        }
        // stage B: 4 butterflies interleaved (amortize shfl latency)
        #pragma unroll
        for (int s = 0; s < SITES_PER_BLK; ++s) up[s] += __shfl_xor(up[s], 1, 64);
        float e4[SITES_PER_BLK], se4[SITES_PER_BLK];
        #pragma unroll
        for (int s = 0; s < SITES_PER_BLK; ++s) { e4[s] = __expf(up[s]); se4[s] = e4[s]; }
        #pragma unroll
        for (int m = 2; m < 64; m <<= 1) {
            #pragma unroll
            for (int s = 0; s < SITES_PER_BLK; ++s) se4[s] += __shfl_xor(se4[s], m, 64);
        }
        // stage C: accumulate
        #pragma unroll
        for (int s = 0; s < SITES_PER_BLK; ++s) {
            const float c = e4[s] * __builtin_amdgcn_rcpf(se4[s]);
            #pragma unroll
            for (int j = 0; j < 8; ++j) sacc[s][j] += c * po[s][j];
        }
    }
}

// ---------------- k_sweep<PASS>: recompute po, accumulate s partials -------
// grid (196, 6), block 256 = 4 waves. wave w owns rows kk = rg*48 + w + 4r.
// R7 fix: register double-buffer for wr (W-load latency was the common cost:
// pass1 == pass2 == 45.8us in R6 -> softmax hidden, W-latency serial).
// 2-step row loop: prefetch next row's 8 uint4 while computing current.
template<int PASS>
__global__ __launch_bounds__(256, 2) void k_sweep(
    const uint4* __restrict__ Wh, const uint4* __restrict__ xh,
    const float* __restrict__ vbuf, float* __restrict__ partial)
{
    const int t  = threadIdx.x;
    const int w  = t >> 6;
    const int ln = t & 63;
    const int sg = blockIdx.x;
    const int rg = blockIdx.y;
    const int site0 = sg * SITES_PER_BLK;
    const int kk0 = __builtin_amdgcn_readfirstlane(rg * ROWS_PER_BLK + w);

    float v[SITES_PER_BLK][8];
    if (PASS >= 2) {
        #pragma unroll
        for (int s = 0; s < SITES_PER_BLK; ++s) {
            const float4* vp = (const float4*)(vbuf + (size_t)(site0 + s) * BD_ + ln * 8);
            const float4 a = vp[0], bq = vp[1];
            v[s][0]=a.x;  v[s][1]=a.y;  v[s][2]=a.z;  v[s][3]=a.w;
            v[s][4]=bq.x; v[s][5]=bq.y; v[s][6]=bq.z; v[s][7]=bq.w;
            PIN8(v[s]);
        }
    }

    float sacc[SITES_PER_BLK][8];
    #pragma unroll
    for (int s = 0; s < SITES_PER_BLK; ++s)
        #pragma unroll
        for (int j = 0; j < 8; ++j) sacc[s][j] = 0.f;

    const uint4* Wrow = Wh + (size_t)kk0 * 512;   // uniform base (SGPR)
    const uint4* xrow = xh + kk0;

    // prologue: load row 0 into wa; Wrow -> row 1
    uint4 wa[8], wb[8];
    #pragma unroll
    for (int u = 0; u < 8; ++u) wa[u] = Wrow[u * 64 + ln];
    Wrow += 4 * 512;

    #pragma unroll 1
    for (int r = 0; r < ROWS_PER_WAVE; r += 2) {
        // body A: prefetch row r+1 -> wb; compute row r with wa
        #pragma unroll
        for (int u = 0; u < 8; ++u) wb[u] = Wrow[u * 64 + ln];
        Wrow += 4 * 512;
        row_body<PASS>(wa, xrow, site0, v, sacc);
        xrow += 4;
        // body B: prefetch row r+2 -> wa; compute row r+1 with wb
        // (final prefetch over-reads <=3 rows past Wh into xh: in-workspace,
        //  values discarded -- benign)
        #pragma unroll
        for (int u = 0; u < 8; ++u) wa[u] = Wrow[u * 64 + ln];
        Wrow += 4 * 512;
        row_body<PASS>(wb, xrow, site0, v, sacc);
        xrow += 4;
    }

    // cross-wave reduce -> partial[site][rg][p]
    __shared__ float red[4 * BD_];   // 8 KB
    #pragma unroll
    for (int s = 0; s < SITES_PER_BLK; ++s) {
        if (s) __syncthreads();
        float4 r0, r1;
        r0.x=sacc[s][0]; r0.y=sacc[s][1]; r0.z=sacc[s][2]; r0.w=sacc[s][3];
        r1.x=sacc[s][4]; r1.y=sacc[s][5]; r1.z=sacc[s][6]; r1.w=sacc[s][7];
        *(float4*)&red[w * BD_ + ln * 8]     = r0;
        *(float4*)&red[w * BD_ + ln * 8 + 4] = r1;
        __syncthreads();
        #pragma unroll
        for (int pp = 0; pp < 2; ++pp) {
            const int p = t + pp * 256;
            partial[((size_t)(site0 + s) * NRG + rg) * BD_ + p] =
                red[p] + red[BD_ + p] + red[2*BD_ + p] + red[3*BD_ + p];
        }
    }
}

// ---------------- k_reduce<PASS>: sum partials, squash, update v / output --
template<int PASS>
__global__ __launch_bounds__(256) void k_reduce(
    const float* __restrict__ partial, float* __restrict__ vbuf,
    float* __restrict__ out)
{
    const int site = blockIdx.x * 4 + (threadIdx.x >> 6);
    const int ln = threadIdx.x & 63;
    float tv[8] = {0.f,0.f,0.f,0.f,0.f,0.f,0.f,0.f};
    #pragma unroll
    for (int rg = 0; rg < NRG; ++rg) {
        const float4* pp4 = (const float4*)(partial + ((size_t)site * NRG + rg) * BD_ + ln * 8);
        const float4 a = pp4[0], b = pp4[1];
        tv[0]+=a.x; tv[1]+=a.y; tv[2]+=a.z; tv[3]+=a.w;
        tv[4]+=b.x; tv[5]+=b.y; tv[6]+=b.z; tv[7]+=b.w;
    }
    if (PASS == 1) {
        #pragma unroll
        for (int j = 0; j < 8; ++j) tv[j] *= (1.f / 32.f);
    }
    float msq = 0.f;
    #pragma unroll
    for (int j = 0; j < 8; ++j) msq += tv[j] * tv[j];
    msq += __shfl_xor(msq, 1, 64);                 // partner holds other 8 d's
    const float fac = sqrtf(msq) / (1.f + msq);    // squash factor
    if (PASS == 1) {
        #pragma unroll
        for (int j = 0; j < 8; ++j) vbuf[(size_t)site * BD_ + ln * 8 + j] = tv[j] * fac;
    } else if (PASS == 2) {
        #pragma unroll
        for (int j = 0; j < 8; ++j) vbuf[(size_t)site * BD_ + ln * 8 + j] += tv[j] * fac;  // v12
    } else {
        const int b = site / LSZ;
        const int l = site - b * LSZ;
        float* op = out + (size_t)b * BD_ * LSZ + l;
        #pragma unroll
        for (int j = 0; j < 8; ++j) op[(size_t)(ln * 8 + j) * LSZ] = tv[j] * fac;
    }
}

extern "C" void kernel_launch(void* const* d_in, const int* in_sizes, int n_in,
                              void* d_out, int out_size, void* d_ws, size_t ws_size,
                              hipStream_t stream) {
    const float* pose = (const float*)d_in[0];
    const float* W    = (const float*)d_in[1];
    float* out        = (float*)d_out;

    if (ws_size < (size_t)WS_NEED) return;

    uint8_t* ws = (uint8_t*)d_ws;
    uint4*  Wh     = (uint4*)  (ws + WH_OFF);
    uint4*  xh     = (uint4*)  (ws + XH_OFF);
    float* partial = (float*)  (ws + PART_OFF);
    float* vbuf    = (float*)  (ws + VBUF_OFF);

    k_prep<<<dim3(NSITES + 72), dim3(256), 0, stream>>>(pose, W, Wh, xh);

    const dim3 gs(NSITES / SITES_PER_BLK, NRG);   // (196, 6)
    k_sweep<1><<<gs, dim3(256), 0, stream>>>(Wh, xh, vbuf, partial);
    k_reduce<1><<<dim3(NSITES / 4), dim3(256), 0, stream>>>(partial, vbuf, out);
    k_sweep<2><<<gs, dim3(256), 0, stream>>>(Wh, xh, vbuf, partial);
    k_reduce<2><<<dim3(NSITES / 4), dim3(256), 0, stream>>>(partial, vbuf, out);
    k_sweep<3><<<gs, dim3(256), 0, stream>>>(Wh, xh, vbuf, partial);
    k_reduce<3><<<dim3(NSITES / 4), dim3(256), 0, stream>>>(partial, vbuf, out);
}

// Round 15
// 182.778 us; speedup vs baseline: 1.1442x; 1.1442x over previous
//
#include <hip/hip_runtime.h>
#include <stdint.h>

// Problem constants
#define NSITES 784          // 4 * 196
#define LSZ    196          // 14*14
#define HWD    14
#define KKA_   288
#define BD_    512
#define NRG    6            // row-groups (288/48)
#define ROWS_PER_BLK 48
#define NW     8            // waves per block (R15: TLP 2x, was 4)
#define ROWS_PER_WAVE 6     // 48 / 8 waves
#define SITES_PER_BLK 4

// workspace layout (bytes)
#define WH_OFF    0            // W fp16 (transposed): 288*512*8*2 = 2,359,296
#define XH_OFF    2359296      // x fp16: 784*288*8*2      = 3,612,672
#define PART_OFF  5971968      // partial: 784*6*512*4     = 9,633,792
#define VBUF_OFF  15605760     // v: 784*512*4             = 1,605,632
#define WS_NEED   17211392

typedef _Float16 h2 __attribute__((ext_vector_type(2)));

// keep 8 floats pinned in VGPRs
#define PIN8(p) asm volatile("" : "+v"(p[0]),"+v"(p[1]),"+v"(p[2]),"+v"(p[3]), \
                                  "+v"(p[4]),"+v"(p[5]),"+v"(p[6]),"+v"(p[7]))

// 8-term fp16 dot with fp32 accumulate
__device__ __forceinline__ float dot8(const uint4 wv, const uint4 xv) {
    h2 w0 = __builtin_bit_cast(h2, wv.x), w1 = __builtin_bit_cast(h2, wv.y),
       w2 = __builtin_bit_cast(h2, wv.z), w3 = __builtin_bit_cast(h2, wv.w);
    h2 x0 = __builtin_bit_cast(h2, xv.x), x1 = __builtin_bit_cast(h2, xv.y),
       x2 = __builtin_bit_cast(h2, xv.z), x3 = __builtin_bit_cast(h2, xv.w);
#if __has_builtin(__builtin_amdgcn_fdot2)
    float acc = __builtin_amdgcn_fdot2(w0, x0, 0.f, false);
    acc = __builtin_amdgcn_fdot2(w1, x1, acc, false);
    acc = __builtin_amdgcn_fdot2(w2, x2, acc, false);
    acc = __builtin_amdgcn_fdot2(w3, x3, acc, false);
    return acc;
#else
    float acc = (float)w0.x*(float)x0.x + (float)w0.y*(float)x0.y
              + (float)w1.x*(float)x1.x + (float)w1.y*(float)x1.y
              + (float)w2.x*(float)x2.x + (float)w2.y*(float)x2.y
              + (float)w3.x*(float)x3.x + (float)w3.y*(float)x3.y;
    return acc;
#endif
}

// ---------------- k_prep: W -> fp16 (transposed), x-patch gather -> fp16 ----
__global__ __launch_bounds__(256) void k_prep(
    const float* __restrict__ pose, const float* __restrict__ W,
    uint4* __restrict__ Wh, uint4* __restrict__ xh)
{
    const int t  = threadIdx.x;
    const int bx = blockIdx.x;
    if (bx < NSITES) {
        const int site = bx;
        const int b = site / LSZ;
        const int l = site - b * LSZ;
        const int oh = l / HWD, ow = l - oh * HWD;
        for (int kk = t; kk < KKA_; kk += 256) {
            const int p = kk >> 5, a = kk & 31;
            const int ky = p / 3 - 1, kx = p % 3 - 1;
            const int y = oh + ky, x = ow + kx;
            const bool inb = (y >= 0 && y < HWD && x >= 0 && x < HWD);
            const float* pp = pose + ((size_t)b * 256 + a * 8) * LSZ
                            + (inb ? (y * HWD + x) : 0);
            uint32_t uo[4];
            #pragma unroll
            for (int cp = 0; cp < 4; ++cp) {
                const float f0 = inb ? pp[(2*cp)   * LSZ] : 0.f;
                const float f1 = inb ? pp[(2*cp+1) * LSZ] : 0.f;
                h2 hh; hh.x = (_Float16)f0; hh.y = (_Float16)f1;
                uo[cp] = __builtin_bit_cast(uint32_t, hh);
            }
            uint4 o; o.x = uo[0]; o.y = uo[1]; o.z = uo[2]; o.w = uo[3];
            xh[(size_t)site * KKA_ + kk] = o;
        }
    } else {
        const int wb = bx - NSITES;
        const int kk = wb * 4 + (t >> 6);
        const int ln = t & 63;
        const float* Wr = W + (size_t)kk * (BD_ * 8);
        #pragma unroll
        for (int u = 0; u < 8; ++u) {
            const int p = ln * 8 + u;
            const float4 fa = *(const float4*)(Wr + p * 8);
            const float4 fb = *(const float4*)(Wr + p * 8 + 4);
            uint32_t uo[4];
            h2 h0; h0.x=(_Float16)fa.x; h0.y=(_Float16)fa.y; uo[0]=__builtin_bit_cast(uint32_t,h0);
            h2 h1; h1.x=(_Float16)fa.z; h1.y=(_Float16)fa.w; uo[1]=__builtin_bit_cast(uint32_t,h1);
            h2 hv; hv.x=(_Float16)fb.x; hv.y=(_Float16)fb.y; uo[2]=__builtin_bit_cast(uint32_t,hv);
            h2 h3; h3.x=(_Float16)fb.z; h3.y=(_Float16)fb.w; uo[3]=__builtin_bit_cast(uint32_t,h3);
            uint4 o; o.x=uo[0]; o.y=uo[1]; o.z=uo[2]; o.w=uo[3];
            Wh[(size_t)kk * 512 + u * 64 + ln] = o;   // coalesced over ln
        }
    }
}

// ---------------- k_sweep<PASS>: recompute po, accumulate s partials -------
// R15: 8 waves/block (512 thr), 6 rows/wave -> 9408 total waves (~9/SIMD
// available vs 4.6 before). Theory: R6 showed each wave ~27% VALU-duty,
// ~73% stalled on L2/shfl latency, with only ~2 resident waves/SIMD; ILP
// fixes (R8/R14 dbuf, VGPR=68 proved compiler sank the prefetch) failed,
// so raise TLP at constant total work. Inner loop = R6's known-good form.
template<int PASS>
__global__ __launch_bounds__(512, 4) void k_sweep(
    const uint4* __restrict__ Wh, const uint4* __restrict__ xh,
    const float* __restrict__ vbuf, float* __restrict__ partial)
{
    const int t  = threadIdx.x;
    const int w  = t >> 6;           // 0..7
    const int ln = t & 63;
    const int sg = blockIdx.x;
    const int rg = blockIdx.y;
    const int site0 = sg * SITES_PER_BLK;
    const int kk0 = __builtin_amdgcn_readfirstlane(rg * ROWS_PER_BLK + w);

    float v[SITES_PER_BLK][8];
    if (PASS >= 2) {
        #pragma unroll
        for (int s = 0; s < SITES_PER_BLK; ++s) {
            const float4* vp = (const float4*)(vbuf + (size_t)(site0 + s) * BD_ + ln * 8);
            const float4 a = vp[0], bq = vp[1];
            v[s][0]=a.x;  v[s][1]=a.y;  v[s][2]=a.z;  v[s][3]=a.w;
            v[s][4]=bq.x; v[s][5]=bq.y; v[s][6]=bq.z; v[s][7]=bq.w;
            PIN8(v[s]);
        }
    }

    float sacc[SITES_PER_BLK][8];
    #pragma unroll
    for (int s = 0; s < SITES_PER_BLK; ++s)
        #pragma unroll
        for (int j = 0; j < 8; ++j) sacc[s][j] = 0.f;

    const uint4* Wrow = Wh + (size_t)kk0 * 512;   // uniform base (SGPR)
    const uint4* xrow = xh + kk0;

    #pragma unroll 1
    for (int r = 0; r < ROWS_PER_WAVE; ++r) {
        uint4 wr[8];
        #pragma unroll
        for (int u = 0; u < 8; ++u) wr[u] = Wrow[u * 64 + ln];  // 1KB coalesced
        Wrow += NW * 512;

        #pragma unroll
        for (int s = 0; s < SITES_PER_BLK; ++s) {
            const uint4 xr = xrow[(size_t)(site0 + s) * KKA_];  // uniform -> s_load
            float po[8];
            #pragma unroll
            for (int j = 0; j < 8; ++j) po[j] = dot8(wr[j], xr);
            if (PASS == 1) {
                #pragma unroll
                for (int j = 0; j < 8; ++j) sacc[s][j] += po[j];
            } else {
                float up = v[s][0] * po[0];
                #pragma unroll
                for (int j = 1; j < 8; ++j) up += v[s][j] * po[j];
                up += __shfl_xor(up, 1, 64);          // full D=16 dot
                const float e = __expf(up);           // logits bounded, no max
                float se = e;
                se += __shfl_xor(se, 2, 64);
                se += __shfl_xor(se, 4, 64);
                se += __shfl_xor(se, 8, 64);
                se += __shfl_xor(se, 16, 64);
                se += __shfl_xor(se, 32, 64);
                const float c = e * __builtin_amdgcn_rcpf(se);
                #pragma unroll
                for (int j = 0; j < 8; ++j) sacc[s][j] += c * po[j];
            }
        }
        xrow += NW;
    }

    // cross-wave reduce -> partial[site][rg][p]
    __shared__ float red[NW * BD_];   // 16 KB
    #pragma unroll
    for (int s = 0; s < SITES_PER_BLK; ++s) {
        if (s) __syncthreads();
        float4 r0, r1;
        r0.x=sacc[s][0]; r0.y=sacc[s][1]; r0.z=sacc[s][2]; r0.w=sacc[s][3];
        r1.x=sacc[s][4]; r1.y=sacc[s][5]; r1.z=sacc[s][6]; r1.w=sacc[s][7];
        *(float4*)&red[w * BD_ + ln * 8]     = r0;
        *(float4*)&red[w * BD_ + ln * 8 + 4] = r1;
        __syncthreads();
        {
            const int p = t;          // 512 threads = 512 p values
            float acc = red[p];
            #pragma unroll
            for (int ww = 1; ww < NW; ++ww) acc += red[ww * BD_ + p];
            partial[((size_t)(site0 + s) * NRG + rg) * BD_ + p] = acc;
        }
    }
}

// ---------------- k_reduce<PASS>: sum partials, squash, update v / output --
template<int PASS>
__global__ __launch_bounds__(256) void k_reduce(
    const float* __restrict__ partial, float* __restrict__ vbuf,
    float* __restrict__ out)
{
    const int site = blockIdx.x * 4 + (threadIdx.x >> 6);
    const int ln = threadIdx.x & 63;
    float tv[8] = {0.f,0.f,0.f,0.f,0.f,0.f,0.f,0.f};
    #pragma unroll
    for (int rg = 0; rg < NRG; ++rg) {
        const float4* pp4 = (const float4*)(partial + ((size_t)site * NRG + rg) * BD_ + ln * 8);
        const float4 a = pp4[0], b = pp4[1];
        tv[0]+=a.x; tv[1]+=a.y; tv[2]+=a.z; tv[3]+=a.w;
        tv[4]+=b.x; tv[5]+=b.y; tv[6]+=b.z; tv[7]+=b.w;
    }
    if (PASS == 1) {
        #pragma unroll
        for (int j = 0; j < 8; ++j) tv[j] *= (1.f / 32.f);
    }
    float msq = 0.f;
    #pragma unroll
    for (int j = 0; j < 8; ++j) msq += tv[j] * tv[j];
    msq += __shfl_xor(msq, 1, 64);                 // partner holds other 8 d's
    const float fac = sqrtf(msq) / (1.f + msq);    // squash factor
    if (PASS == 1) {
        #pragma unroll
        for (int j = 0; j < 8; ++j) vbuf[(size_t)site * BD_ + ln * 8 + j] = tv[j] * fac;
    } else if (PASS == 2) {
        #pragma unroll
        for (int j = 0; j < 8; ++j) vbuf[(size_t)site * BD_ + ln * 8 + j] += tv[j] * fac;  // v12
    } else {
        const int b = site / LSZ;
        const int l = site - b * LSZ;
        float* op = out + (size_t)b * BD_ * LSZ + l;
        #pragma unroll
        for (int j = 0; j < 8; ++j) op[(size_t)(ln * 8 + j) * LSZ] = tv[j] * fac;
    }
}

extern "C" void kernel_launch(void* const* d_in, const int* in_sizes, int n_in,
                              void* d_out, int out_size, void* d_ws, size_t ws_size,
                              hipStream_t stream) {
    const float* pose = (const float*)d_in[0];
    const float* W    = (const float*)d_in[1];
    float* out        = (float*)d_out;

    if (ws_size < (size_t)WS_NEED) return;

    uint8_t* ws = (uint8_t*)d_ws;
    uint4*  Wh     = (uint4*)  (ws + WH_OFF);
    uint4*  xh     = (uint4*)  (ws + XH_OFF);
    float* partial = (float*)  (ws + PART_OFF);
    float* vbuf    = (float*)  (ws + VBUF_OFF);

    k_prep<<<dim3(NSITES + 72), dim3(256), 0, stream>>>(pose, W, Wh, xh);

    const dim3 gs(NSITES / SITES_PER_BLK, NRG);   // (196, 6)
    k_sweep<1><<<gs, dim3(512), 0, stream>>>(Wh, xh, vbuf, partial);
    k_reduce<1><<<dim3(NSITES / 4), dim3(256), 0, stream>>>(partial, vbuf, out);
    k_sweep<2><<<gs, dim3(512), 0, stream>>>(Wh, xh, vbuf, partial);
    k_reduce<2><<<dim3(NSITES / 4), dim3(256), 0, stream>>>(partial, vbuf, out);
    k_sweep<3><<<gs, dim3(512), 0, stream>>>(Wh, xh, vbuf, partial);
    k_reduce<3><<<dim3(NSITES / 4), dim3(256), 0, stream>>>(partial, vbuf, out);
}